// Round 5
// baseline (211.667 us; speedup 1.0000x reference)
//
#include <hip/hip_runtime.h>
#include <hip/hip_bf16.h>
#include <math.h>

#define BB   64
#define TT   1000
#define DEC  1024
#define ENCD 512
#define ATT  128
#define FILT 32
#define KSZ  31
#define PADW 15
#define BT   128   // t-tile per block
#define KC   64    // K chunk (bf16)
#define XW   (BT + KSZ - 1)   // 158

typedef __attribute__((ext_vector_type(8))) short bf16x8;
typedef __attribute__((ext_vector_type(4))) float f32x4;

static __device__ __forceinline__ ushort f2bf(float f) {
    union { float f; unsigned u; } v; v.f = f;
    unsigned r = (v.u + 0x7FFFu + ((v.u >> 16) & 1u)) >> 16;   // RNE
    return (ushort)r;
}

// ---------------- K0: pack B into fragment-major bf16 layout ------------------
// element index = (((c*2+ks)*8 + n)*64 + lane)*8 + j
//   a = n*16 + (lane&15),  k = c*64 + ks*32 + (lane>>4)*8 + j
//   k<512: key_w[a][k];  512<=k<544: loc_proj_w[a][k-512];  else 0
__global__ __launch_bounds__(256) void k_prep(const float* __restrict__ kw,
                                              const float* __restrict__ lpw,
                                              ushort* __restrict__ kwbF) {
    int idx = blockIdx.x * 256 + threadIdx.x;     // 0..9215
    int l  = idx & 63;
    int n  = (idx >> 6) & 7;
    int ks = (idx >> 9) & 1;
    int c  = idx >> 10;
    if (c >= 9) return;
    int a  = n * 16 + (l & 15);
    int k0 = c * 64 + ks * 32 + (l >> 4) * 8;
    ushort u[8];
    #pragma unroll
    for (int j = 0; j < 8; ++j) {
        int k = k0 + j;
        float v = 0.f;
        if (k < ENCD)             v = kw[a * ENCD + k];
        else if (k < ENCD + FILT) v = lpw[a * FILT + (k - ENCD)];
        u[j] = f2bf(v);
    }
    *(uint4*)&kwbF[(size_t)idx * 8] = *(const uint4*)u;
}

// ---------------- K1: query = decoder_hidden @ query_w^T  (64 x 128) ----------
__global__ __launch_bounds__(128) void k_query(const float* __restrict__ dh,
                                               const float* __restrict__ qw,
                                               float* __restrict__ q) {
    int b = blockIdx.x, a = threadIdx.x;
    const float* dhb = dh + b * DEC;
    const float* qwa = qw + a * DEC;
    float s = 0.f;
    #pragma unroll 4
    for (int k = 0; k < DEC; k += 4) {
        float4 x = *(const float4*)&dhb[k];
        float4 w = *(const float4*)&qwa[k];
        s += x.x * w.x + x.y * w.y + x.z * w.z + x.w * w.w;
    }
    q[b * ATT + a] = s;
}

// ---------------- K3: fused conv + double-buffered LDS MFMA GEMM --------------
__global__ __launch_bounds__(512, 4) void k_energies(
    const float* __restrict__ enc, const float* __restrict__ pw,
    const float* __restrict__ pwc, const float* __restrict__ cwg,
    const ushort* __restrict__ kwbF, const float* __restrict__ vw,
    const float* __restrict__ q, float* __restrict__ energ)
{
    __shared__ __align__(16) ushort Ab[2][BT * KC];        // 2 x 16 KB, swizzled
    __shared__ __align__(16) ushort Bb[2][2 * 8 * 64 * 8]; // 2 x 16 KB, frag-major
    __shared__ __align__(16) ushort featb[BT * FILT];      // 8 KB, compact swizzled
    // conv-phase overlays (dead until chunk-0 compute begins):
    float* cwl   = (float*)Ab[1];    // 1984 floats
    float* convx = (float*)Bb[1];    // 2 x 158 floats

    const int b   = blockIdx.x;
    const int t0  = blockIdx.y * BT;
    const int tid = threadIdx.x;
    const int w   = tid >> 6;
    const int l   = tid & 63;
    const int r   = l & 15;
    const int sl  = l >> 4;
    const int row = w * 16 + r;      // wave's t-row for MFMA reads

    const float* encb = enc + (size_t)b * TT * ENCD;

    // ---- issue chunk-0 staging loads (regs) ----
    float4 areg[4];
    uint4  breg[2];
    #pragma unroll
    for (int j = 0; j < 4; ++j) {
        int idx = tid + j * 512;
        int rw = idx >> 4, c4 = idx & 15;
        int tg = t0 + rw; if (tg >= TT) tg = TT - 1;
        areg[j] = *(const float4*)(encb + (size_t)tg * ENCD + c4 * 4);
    }
    #pragma unroll
    for (int j = 0; j < 2; ++j)
        breg[j] = *(const uint4*)(kwbF + (size_t)(tid + j * 512) * 8);

    // ---- conv staging (into overlays) ----
    if (tid < 496) {
        float4 v = *(const float4*)(cwg + tid * 4);
        *(float4*)&cwl[tid * 4] = v;
    }
    for (int i = tid; i < 2 * XW; i += 512) {
        int c  = i / XW;
        int tt = i - c * XW;
        int tg = t0 + tt - PADW;
        const float* src = c ? pwc : pw;
        convx[c * XW + tt] = (tg >= 0 && tg < TT) ? src[b * TT + tg] : 0.f;
    }
    __syncthreads();

    // ---- conv compute -> featb (compact [128][32], swizzled) ----
    #pragma unroll
    for (int i = 0; i < 8; ++i) {
        int idx = tid + i * 512;          // 0..4095
        int f = idx >> 7, tl = idx & 127;
        const float* c0 = cwl + (f * 2 + 0) * KSZ;
        const float* c1 = cwl + (f * 2 + 1) * KSZ;
        float s = 0.f;
        #pragma unroll
        for (int k = 0; k < KSZ; ++k)
            s += c0[k] * convx[tl + k] + c1[k] * convx[XW + tl + k];
        int byte = tl * 64 + ((((f >> 3) ^ (tl & 3)) << 4)) + (f & 7) * 2;
        *(ushort*)((char*)featb + byte) = f2bf(s);
    }

    // ---- write chunk-0 staging into LDS buf 0 ----
    #pragma unroll
    for (int j = 0; j < 4; ++j) {
        int idx = tid + j * 512;
        int rw = idx >> 4, c4 = idx & 15;
        ushort u[4] = { f2bf(areg[j].x), f2bf(areg[j].y), f2bf(areg[j].z), f2bf(areg[j].w) };
        int byte = rw * 128 + ((((c4 >> 1) ^ (rw & 7)) << 4)) + (c4 & 1) * 8;
        *(uint2*)((char*)Ab[0] + byte) = *(const uint2*)u;
    }
    #pragma unroll
    for (int j = 0; j < 2; ++j)
        *(uint4*)&Bb[0][(size_t)(tid + j * 512) * 8] = breg[j];
    __syncthreads();   // featb + A0 + B0 ready; overlays dead from here

    // ---- MFMA K-loop: 8 enc chunks, double-buffered ----
    f32x4 acc[8];
    #pragma unroll
    for (int n = 0; n < 8; ++n) acc[n] = (f32x4){0.f, 0.f, 0.f, 0.f};

    bf16x8 bfeat[8];
    int buf = 0;
    for (int c = 0; c < 8; ++c) {
        // issue next-chunk staging loads (T14: issue early, write late)
        if (c < 7) {
            #pragma unroll
            for (int j = 0; j < 4; ++j) {
                int idx = tid + j * 512;
                int rw = idx >> 4, c4 = idx & 15;
                int tg = t0 + rw; if (tg >= TT) tg = TT - 1;
                areg[j] = *(const float4*)(encb + (size_t)tg * ENCD + (c + 1) * KC + c4 * 4);
            }
            #pragma unroll
            for (int j = 0; j < 2; ++j)
                breg[j] = *(const uint4*)(kwbF + (size_t)(c + 1) * 8192 + (size_t)(tid + j * 512) * 8);
        } else {
            // feat-chunk B fragments, direct from L2 (once per thread-block pass)
            #pragma unroll
            for (int n = 0; n < 8; ++n)
                bfeat[n] = *(const bf16x8*)(kwbF + (size_t)(128 + n) * 512 + l * 8);
        }

        // compute chunk c from LDS buf
        #pragma unroll
        for (int ks = 0; ks < 2; ++ks) {
            int s = ks * 4 + sl;
            bf16x8 af = *(const bf16x8*)((const char*)Ab[buf] + row * 128 + (((s ^ (row & 7)) << 4)));
            #pragma unroll
            for (int n = 0; n < 8; ++n) {
                bf16x8 bv = *(const bf16x8*)&Bb[buf][(size_t)((ks * 8 + n) * 64 + l) * 8];
                acc[n] = __builtin_amdgcn_mfma_f32_16x16x32_bf16(af, bv, acc[n], 0, 0, 0);
            }
        }

        // write staged regs into the other buffer
        if (c < 7) {
            #pragma unroll
            for (int j = 0; j < 4; ++j) {
                int idx = tid + j * 512;
                int rw = idx >> 4, c4 = idx & 15;
                ushort u[4] = { f2bf(areg[j].x), f2bf(areg[j].y), f2bf(areg[j].z), f2bf(areg[j].w) };
                int byte = rw * 128 + ((((c4 >> 1) ^ (rw & 7)) << 4)) + (c4 & 1) * 8;
                *(uint2*)((char*)Ab[buf ^ 1] + byte) = *(const uint2*)u;
            }
            #pragma unroll
            for (int j = 0; j < 2; ++j)
                *(uint4*)&Bb[buf ^ 1][(size_t)(tid + j * 512) * 8] = breg[j];
        }
        __syncthreads();
        buf ^= 1;
    }

    // ---- feat chunk (K=32): A from featb, B from regs ----
    {
        bf16x8 af = *(const bf16x8*)((const char*)featb + row * 64 + (((sl ^ (row & 3)) << 4)));
        #pragma unroll
        for (int n = 0; n < 8; ++n)
            acc[n] = __builtin_amdgcn_mfma_f32_16x16x32_bf16(af, bfeat[n], acc[n], 0, 0, 0);
    }

    // ---- epilogue: + query, tanh, v-dot, reduce over a ----
    const float* qb = q + b * ATT;
    float vv[8], qv[8];
    #pragma unroll
    for (int n = 0; n < 8; ++n) {
        int a = n * 16 + r;
        vv[n] = vw[a];
        qv[n] = qb[a];
    }
    float pe[4];
    #pragma unroll
    for (int rr = 0; rr < 4; ++rr) {
        float s = 0.f;
        #pragma unroll
        for (int n = 0; n < 8; ++n)
            s += vv[n] * tanhf(acc[n][rr] + qv[n]);
        pe[rr] = s;
    }
    #pragma unroll
    for (int m = 1; m < 16; m <<= 1) {
        #pragma unroll
        for (int rr = 0; rr < 4; ++rr)
            pe[rr] += __shfl_xor(pe[rr], m, 64);
    }
    if (r == 0) {
        #pragma unroll
        for (int rr = 0; rr < 4; ++rr) {
            int t = t0 + w * 16 + sl * 4 + rr;
            if (t < TT) energ[b * TT + t] = pe[rr];
        }
    }
}

// ---------------- K4: softmax over T per batch row ----------------------------
__global__ __launch_bounds__(256) void k_softmax(const float* __restrict__ energ,
                                                 const unsigned char* __restrict__ mask,
                                                 float* __restrict__ wout) {
    int b = blockIdx.x, tid = threadIdx.x;
    __shared__ float sred[8];
    const float* eb = energ + b * TT;
    const unsigned char* mb = mask + b * TT;
    float m = -INFINITY;
    for (int t = tid; t < TT; t += 256) {
        float e = mb[t] ? -INFINITY : eb[t];
        m = fmaxf(m, e);
    }
    #pragma unroll
    for (int off = 32; off; off >>= 1) m = fmaxf(m, __shfl_xor(m, off, 64));
    if ((tid & 63) == 0) sred[tid >> 6] = m;
    __syncthreads();
    m = fmaxf(fmaxf(sred[0], sred[1]), fmaxf(sred[2], sred[3]));
    float s = 0.f;
    for (int t = tid; t < TT; t += 256) {
        float e = mb[t] ? -INFINITY : eb[t];
        s += expf(e - m);
    }
    #pragma unroll
    for (int off = 32; off; off >>= 1) s += __shfl_xor(s, off, 64);
    if ((tid & 63) == 0) sred[4 + (tid >> 6)] = s;
    __syncthreads();
    s = sred[4] + sred[5] + sred[6] + sred[7];
    float inv = 1.f / s;
    float* wb = wout + b * TT;
    for (int t = tid; t < TT; t += 256) {
        float e = mb[t] ? -INFINITY : eb[t];
        wb[t] = expf(e - m) * inv;
    }
}

// ---------------- K5: partial context (8 t-chunks of 125) ---------------------
#define TCH 125
__global__ __launch_bounds__(512) void k_ctx_partial(const float* __restrict__ enc,
                                                     const float* __restrict__ w,
                                                     float* __restrict__ partial) {
    int b = blockIdx.x, c = blockIdx.y;
    int e = threadIdx.x;
    __shared__ float sw[TCH];
    int tstart = c * TCH;
    if (threadIdx.x < TCH) sw[threadIdx.x] = w[b * TT + tstart + threadIdx.x];
    __syncthreads();
    const float* p = enc + ((size_t)b * TT + tstart) * ENCD + e;
    float acc = 0.f;
    #pragma unroll 5
    for (int t = 0; t < TCH; ++t)
        acc += sw[t] * p[(size_t)t * ENCD];
    partial[((b << 3) + c) * ENCD + e] = acc;
}

// ---------------- K6: reduce partials -> context ------------------------------
__global__ __launch_bounds__(512) void k_ctx_reduce(const float* __restrict__ partial,
                                                    float* __restrict__ ctx) {
    int b = blockIdx.x, e = threadIdx.x;
    float s = 0.f;
    #pragma unroll
    for (int c = 0; c < 8; ++c) s += partial[((b << 3) + c) * ENCD + e];
    ctx[b * ENCD + e] = s;
}

// ---------------- launcher ----------------------------------------------------
extern "C" void kernel_launch(void* const* d_in, const int* in_sizes, int n_in,
                              void* d_out, int out_size, void* d_ws, size_t ws_size,
                              hipStream_t stream) {
    const float* dh   = (const float*)d_in[0];
    const float* enc  = (const float*)d_in[1];
    const float* pw   = (const float*)d_in[2];
    const float* pwc  = (const float*)d_in[3];
    const unsigned char* mask = (const unsigned char*)d_in[4];
    const float* cw   = (const float*)d_in[5];
    const float* lpw  = (const float*)d_in[6];
    const float* qw   = (const float*)d_in[7];
    const float* kw   = (const float*)d_in[8];
    const float* vw   = (const float*)d_in[9];

    float* out_ctx = (float*)d_out;                 // (64, 512)
    float* out_w   = out_ctx + BB * ENCD;           // (64, 1000)

    float* wsf   = (float*)d_ws;
    float*  q     = wsf;                             // 8192 f
    float*  energ = wsf + 8192;                      // 64000 f
    float*  part  = wsf + 8192 + 64000;              // 32768 f
    ushort* kwbF  = (ushort*)(wsf + 8192 + 64000 + 32768);  // 73728 bf16

    k_prep    <<<dim3(36),    dim3(256), 0, stream>>>(kw, lpw, kwbF);
    k_query   <<<dim3(BB),    dim3(128), 0, stream>>>(dh, qw, q);
    k_energies<<<dim3(BB, 8), dim3(512), 0, stream>>>(enc, pw, pwc, cw, kwbF, vw, q, energ);
    k_softmax <<<dim3(BB),    dim3(256), 0, stream>>>(energ, mask, out_w);
    k_ctx_partial<<<dim3(BB, 8), dim3(512), 0, stream>>>(enc, out_w, part);
    k_ctx_reduce <<<dim3(BB),    dim3(512), 0, stream>>>(part, out_ctx);
}

// Round 6
// 142.219 us; speedup vs baseline: 1.4883x; 1.4883x over previous
//
#include <hip/hip_runtime.h>
#include <hip/hip_bf16.h>
#include <math.h>

#define BB   64
#define TT   1000
#define DEC  1024
#define ENCD 512
#define ATT  128
#define FILT 32
#define KSZ  31
#define PADW 15
#define BT   128   // t-tile per block
#define KC   64    // K chunk (bf16)
#define XW   (BT + KSZ - 1)   // 158

typedef __attribute__((ext_vector_type(8))) short bf16x8;
typedef __attribute__((ext_vector_type(4))) float f32x4;

static __device__ __forceinline__ ushort f2bf(float f) {
    union { float f; unsigned u; } v; v.f = f;
    unsigned r = (v.u + 0x7FFFu + ((v.u >> 16) & 1u)) >> 16;   // RNE
    return (ushort)r;
}

// async global->LDS, 16B per lane; LDS dest = wave-uniform base + lane*16
static __device__ __forceinline__ void gl2lds16(const void* g, void* l) {
    __builtin_amdgcn_global_load_lds(
        (const __attribute__((address_space(1))) unsigned*)g,
        (__attribute__((address_space(3))) unsigned*)l, 16, 0, 0);
}

// ---------------- K0: pack B into fragment-major bf16 layout ------------------
// element index = (((c*2+ks)*8 + n)*64 + lane)*8 + j
//   a = n*16 + (lane&15),  k = c*64 + ks*32 + (lane>>4)*8 + j
//   k<512: key_w[a][k];  512<=k<544: loc_proj_w[a][k-512];  else 0
__global__ __launch_bounds__(256) void k_prep(const float* __restrict__ kw,
                                              const float* __restrict__ lpw,
                                              ushort* __restrict__ kwbF) {
    int idx = blockIdx.x * 256 + threadIdx.x;     // 0..9215
    int l  = idx & 63;
    int n  = (idx >> 6) & 7;
    int ks = (idx >> 9) & 1;
    int c  = idx >> 10;
    if (c >= 9) return;
    int a  = n * 16 + (l & 15);
    int k0 = c * 64 + ks * 32 + (l >> 4) * 8;
    ushort u[8];
    #pragma unroll
    for (int j = 0; j < 8; ++j) {
        int k = k0 + j;
        float v = 0.f;
        if (k < ENCD)             v = kw[a * ENCD + k];
        else if (k < ENCD + FILT) v = lpw[a * FILT + (k - ENCD)];
        u[j] = f2bf(v);
    }
    *(uint4*)&kwbF[(size_t)idx * 8] = *(const uint4*)u;
}

// ---------------- K1: query = decoder_hidden @ query_w^T  (64 x 128) ----------
__global__ __launch_bounds__(128) void k_query(const float* __restrict__ dh,
                                               const float* __restrict__ qw,
                                               float* __restrict__ q) {
    int b = blockIdx.x, a = threadIdx.x;
    const float* dhb = dh + b * DEC;
    const float* qwa = qw + a * DEC;
    float s = 0.f;
    #pragma unroll 4
    for (int k = 0; k < DEC; k += 4) {
        float4 x = *(const float4*)&dhb[k];
        float4 w = *(const float4*)&qwa[k];
        s += x.x * w.x + x.y * w.y + x.z * w.z + x.w * w.w;
    }
    q[b * ATT + a] = s;
}

// ---------------- K3: fused conv + double-buffered LDS MFMA GEMM --------------
__global__ __launch_bounds__(512) void k_energies(
    const float* __restrict__ enc, const float* __restrict__ pw,
    const float* __restrict__ pwc, const float* __restrict__ cwg,
    const ushort* __restrict__ kwbF, const float* __restrict__ vw,
    const float* __restrict__ q, float* __restrict__ energ)
{
    __shared__ __align__(16) ushort Ab[2][BT * KC];        // 2 x 16 KB, swizzled
    __shared__ __align__(16) ushort Bb[2][2 * 8 * 64 * 8]; // 2 x 16 KB, frag-major linear
    __shared__ __align__(16) ushort featb[BT * FILT];      // 8 KB, compact swizzled
    // conv-phase overlays (dead once the main loop begins):
    float* cwl   = (float*)Ab[1];    // 1984 floats
    float* convx = (float*)Bb[1];    // 2 x 158 floats

    const int b   = blockIdx.x;
    const int t0  = blockIdx.y * BT;
    const int tid = threadIdx.x;
    const int w   = tid >> 6;
    const int l   = tid & 63;
    const int r   = l & 15;
    const int sl  = l >> 4;
    const int row = w * 16 + r;      // wave's t-row for MFMA reads

    const float* encb = enc + (size_t)b * TT * ENCD;

    // ---- B0 via async global->LDS (linear layout matches exactly) ----
    #pragma unroll
    for (int j = 0; j < 2; ++j)
        gl2lds16(kwbF + (size_t)(tid + j * 512) * 8,
                 &Bb[0][(size_t)(w * 64 + j * 512) * 8]);

    // ---- chunk-0 A staging loads (regs, coalesced) ----
    float4 areg[4];
    #pragma unroll
    for (int j = 0; j < 4; ++j) {
        int idx = tid + j * 512;
        int rw = idx >> 4, c4 = idx & 15;
        int tg = t0 + rw; if (tg >= TT) tg = TT - 1;
        areg[j] = *(const float4*)(encb + (size_t)tg * ENCD + c4 * 4);
    }

    // ---- conv staging (into overlays) ----
    if (tid < 496) {
        float4 v = *(const float4*)(cwg + tid * 4);
        *(float4*)&cwl[tid * 4] = v;
    }
    for (int i = tid; i < 2 * XW; i += 512) {
        int c  = i / XW;
        int tt = i - c * XW;
        int tg = t0 + tt - PADW;
        const float* src = c ? pwc : pw;
        convx[c * XW + tt] = (tg >= 0 && tg < TT) ? src[b * TT + tg] : 0.f;
    }
    __syncthreads();

    // ---- conv compute -> featb (compact [128][32], swizzled) ----
    #pragma unroll
    for (int i = 0; i < 8; ++i) {
        int idx = tid + i * 512;          // 0..4095
        int f = idx >> 7, tl = idx & 127;
        const float* c0 = cwl + (f * 2 + 0) * KSZ;
        const float* c1 = cwl + (f * 2 + 1) * KSZ;
        float s = 0.f;
        #pragma unroll
        for (int k = 0; k < KSZ; ++k)
            s += c0[k] * convx[tl + k] + c1[k] * convx[XW + tl + k];
        int byte = tl * 64 + ((((f >> 3) ^ (tl & 3)) << 4)) + (f & 7) * 2;
        *(ushort*)((char*)featb + byte) = f2bf(s);
    }

    // ---- write chunk-0 A into LDS buf 0 ----
    #pragma unroll
    for (int j = 0; j < 4; ++j) {
        int idx = tid + j * 512;
        int rw = idx >> 4, c4 = idx & 15;
        ushort u[4] = { f2bf(areg[j].x), f2bf(areg[j].y), f2bf(areg[j].z), f2bf(areg[j].w) };
        int byte = rw * 128 + ((((c4 >> 1) ^ (rw & 7)) << 4)) + (c4 & 1) * 8;
        *(uint2*)((char*)Ab[0] + byte) = *(const uint2*)u;
    }
    __syncthreads();   // drains vmcnt(0): B0 landed; featb + A0 ready; overlays dead

    // ---- MFMA K-loop: 8 enc chunks, double-buffered ----
    f32x4 acc[8];
    #pragma unroll
    for (int n = 0; n < 8; ++n) acc[n] = (f32x4){0.f, 0.f, 0.f, 0.f};

    bf16x8 bfeat[8];
    int buf = 0;
    for (int c = 0; c < 8; ++c) {
        // issue next-chunk staging (T14: issue early, write late)
        if (c < 7) {
            #pragma unroll
            for (int j = 0; j < 2; ++j)
                gl2lds16(kwbF + (size_t)(c + 1) * 8192 + (size_t)(tid + j * 512) * 8,
                         &Bb[buf ^ 1][(size_t)(w * 64 + j * 512) * 8]);
            #pragma unroll
            for (int j = 0; j < 4; ++j) {
                int idx = tid + j * 512;
                int rw = idx >> 4, c4 = idx & 15;
                int tg = t0 + rw; if (tg >= TT) tg = TT - 1;
                areg[j] = *(const float4*)(encb + (size_t)tg * ENCD + (c + 1) * KC + c4 * 4);
            }
        } else {
            // feat-chunk B fragments, direct from L2 (tiny, read once)
            #pragma unroll
            for (int n = 0; n < 8; ++n)
                bfeat[n] = *(const bf16x8*)(kwbF + (size_t)(128 + n) * 512 + l * 8);
        }

        // compute chunk c from LDS buf
        #pragma unroll
        for (int ks = 0; ks < 2; ++ks) {
            int s = ks * 4 + sl;
            bf16x8 af = *(const bf16x8*)((const char*)Ab[buf] + row * 128 + (((s ^ (row & 7)) << 4)));
            #pragma unroll
            for (int n = 0; n < 8; ++n) {
                bf16x8 bv = *(const bf16x8*)&Bb[buf][(size_t)((ks * 8 + n) * 64 + l) * 8];
                acc[n] = __builtin_amdgcn_mfma_f32_16x16x32_bf16(af, bv, acc[n], 0, 0, 0);
            }
        }

        // write staged A regs into the other buffer
        if (c < 7) {
            #pragma unroll
            for (int j = 0; j < 4; ++j) {
                int idx = tid + j * 512;
                int rw = idx >> 4, c4 = idx & 15;
                ushort u[4] = { f2bf(areg[j].x), f2bf(areg[j].y), f2bf(areg[j].z), f2bf(areg[j].w) };
                int byte = rw * 128 + ((((c4 >> 1) ^ (rw & 7)) << 4)) + (c4 & 1) * 8;
                *(uint2*)((char*)Ab[buf ^ 1] + byte) = *(const uint2*)u;
            }
        }
        __syncthreads();   // also drains vmcnt(0) -> next B buffer landed
        buf ^= 1;
    }

    // ---- feat chunk (K=32): A from featb, B from regs ----
    {
        bf16x8 af = *(const bf16x8*)((const char*)featb + row * 64 + (((sl ^ (row & 3)) << 4)));
        #pragma unroll
        for (int n = 0; n < 8; ++n)
            acc[n] = __builtin_amdgcn_mfma_f32_16x16x32_bf16(af, bfeat[n], acc[n], 0, 0, 0);
    }

    // ---- epilogue: + query, tanh, v-dot, reduce over a ----
    const float* qb = q + b * ATT;
    float vv[8], qv[8];
    #pragma unroll
    for (int n = 0; n < 8; ++n) {
        int a = n * 16 + r;
        vv[n] = vw[a];
        qv[n] = qb[a];
    }
    float pe[4];
    #pragma unroll
    for (int rr = 0; rr < 4; ++rr) {
        float s = 0.f;
        #pragma unroll
        for (int n = 0; n < 8; ++n)
            s += vv[n] * tanhf(acc[n][rr] + qv[n]);
        pe[rr] = s;
    }
    #pragma unroll
    for (int m = 1; m < 16; m <<= 1) {
        #pragma unroll
        for (int rr = 0; rr < 4; ++rr)
            pe[rr] += __shfl_xor(pe[rr], m, 64);
    }
    if (r == 0) {
        #pragma unroll
        for (int rr = 0; rr < 4; ++rr) {
            int t = t0 + w * 16 + sl * 4 + rr;
            if (t < TT) energ[b * TT + t] = pe[rr];
        }
    }
}

// ---------------- K4: softmax over T per batch row ----------------------------
__global__ __launch_bounds__(256) void k_softmax(const float* __restrict__ energ,
                                                 const unsigned char* __restrict__ mask,
                                                 float* __restrict__ wout) {
    int b = blockIdx.x, tid = threadIdx.x;
    __shared__ float sred[8];
    const float* eb = energ + b * TT;
    const unsigned char* mb = mask + b * TT;
    float m = -INFINITY;
    for (int t = tid; t < TT; t += 256) {
        float e = mb[t] ? -INFINITY : eb[t];
        m = fmaxf(m, e);
    }
    #pragma unroll
    for (int off = 32; off; off >>= 1) m = fmaxf(m, __shfl_xor(m, off, 64));
    if ((tid & 63) == 0) sred[tid >> 6] = m;
    __syncthreads();
    m = fmaxf(fmaxf(sred[0], sred[1]), fmaxf(sred[2], sred[3]));
    float s = 0.f;
    for (int t = tid; t < TT; t += 256) {
        float e = mb[t] ? -INFINITY : eb[t];
        s += expf(e - m);
    }
    #pragma unroll
    for (int off = 32; off; off >>= 1) s += __shfl_xor(s, off, 64);
    if ((tid & 63) == 0) sred[4 + (tid >> 6)] = s;
    __syncthreads();
    s = sred[4] + sred[5] + sred[6] + sred[7];
    float inv = 1.f / s;
    float* wb = wout + b * TT;
    for (int t = tid; t < TT; t += 256) {
        float e = mb[t] ? -INFINITY : eb[t];
        wb[t] = expf(e - m) * inv;
    }
}

// ---------------- K5: partial context (8 t-chunks of 125) ---------------------
#define TCH 125
__global__ __launch_bounds__(512) void k_ctx_partial(const float* __restrict__ enc,
                                                     const float* __restrict__ w,
                                                     float* __restrict__ partial) {
    int b = blockIdx.x, c = blockIdx.y;
    int e = threadIdx.x;
    __shared__ float sw[TCH];
    int tstart = c * TCH;
    if (threadIdx.x < TCH) sw[threadIdx.x] = w[b * TT + tstart + threadIdx.x];
    __syncthreads();
    const float* p = enc + ((size_t)b * TT + tstart) * ENCD + e;
    float acc = 0.f;
    #pragma unroll 5
    for (int t = 0; t < TCH; ++t)
        acc += sw[t] * p[(size_t)t * ENCD];
    partial[((b << 3) + c) * ENCD + e] = acc;
}

// ---------------- K6: reduce partials -> context ------------------------------
__global__ __launch_bounds__(512) void k_ctx_reduce(const float* __restrict__ partial,
                                                    float* __restrict__ ctx) {
    int b = blockIdx.x, e = threadIdx.x;
    float s = 0.f;
    #pragma unroll
    for (int c = 0; c < 8; ++c) s += partial[((b << 3) + c) * ENCD + e];
    ctx[b * ENCD + e] = s;
}

// ---------------- launcher ----------------------------------------------------
extern "C" void kernel_launch(void* const* d_in, const int* in_sizes, int n_in,
                              void* d_out, int out_size, void* d_ws, size_t ws_size,
                              hipStream_t stream) {
    const float* dh   = (const float*)d_in[0];
    const float* enc  = (const float*)d_in[1];
    const float* pw   = (const float*)d_in[2];
    const float* pwc  = (const float*)d_in[3];
    const unsigned char* mask = (const unsigned char*)d_in[4];
    const float* cw   = (const float*)d_in[5];
    const float* lpw  = (const float*)d_in[6];
    const float* qw   = (const float*)d_in[7];
    const float* kw   = (const float*)d_in[8];
    const float* vw   = (const float*)d_in[9];

    float* out_ctx = (float*)d_out;                 // (64, 512)
    float* out_w   = out_ctx + BB * ENCD;           // (64, 1000)

    float* wsf   = (float*)d_ws;
    float*  q     = wsf;                             // 8192 f
    float*  energ = wsf + 8192;                      // 64000 f
    float*  part  = wsf + 8192 + 64000;              // 32768 f
    ushort* kwbF  = (ushort*)(wsf + 8192 + 64000 + 32768);  // 73728 bf16

    k_prep    <<<dim3(36),    dim3(256), 0, stream>>>(kw, lpw, kwbF);
    k_query   <<<dim3(BB),    dim3(128), 0, stream>>>(dh, qw, q);
    k_energies<<<dim3(BB, 8), dim3(512), 0, stream>>>(enc, pw, pwc, cw, kwbF, vw, q, energ);
    k_softmax <<<dim3(BB),    dim3(256), 0, stream>>>(energ, mask, out_w);
    k_ctx_partial<<<dim3(BB, 8), dim3(512), 0, stream>>>(enc, out_w, part);
    k_ctx_reduce <<<dim3(BB),    dim3(512), 0, stream>>>(part, out_ctx);
}